// Round 3
// baseline (518.853 us; speedup 1.0000x reference)
//
#include <hip/hip_runtime.h>
#include <hip/hip_bf16.h>
#include <math.h>

#define B_   16
#define C_   384
#define C3_  1152
#define HW_  4096
#define NH_  8
#define D_   48

typedef _Float16 f16x8 __attribute__((ext_vector_type(8)));
typedef _Float16 f16x4 __attribute__((ext_vector_type(4)));
typedef _Float16 f16x2 __attribute__((ext_vector_type(2)));
typedef float    f32x4 __attribute__((ext_vector_type(4)));

// ---------------- fp32 -> fp16 weight conversion ----------------
__global__ __launch_bounds__(256) void conv_w_f16(
    const float* __restrict__ w, _Float16* __restrict__ wh, int n4)
{
    int i = blockIdx.x * 256 + threadIdx.x;
    if (i < n4) {
        float4 v = *(const float4*)&w[(size_t)i * 4];
        f16x4 h = { (_Float16)v.x, (_Float16)v.y, (_Float16)v.z, (_Float16)v.w };
        *(f16x4*)&wh[(size_t)i * 4] = h;
    }
}

// ---------------- x [b][384][4096] f32 -> xt [b][4096][384] fp16 ----------------
__global__ __launch_bounds__(256) void transpose_to_f16(
    const float* __restrict__ x, _Float16* __restrict__ xt)
{
    const int b  = blockIdx.z;
    const int k0 = blockIdx.y * 64;
    const int n0 = blockIdx.x * 64;
    __shared__ float sm[64][65];
    const float* xb = x + (size_t)b * C_ * HW_;
    _Float16* xtb = xt + (size_t)b * HW_ * C_;
    const int t = threadIdx.x;
    #pragma unroll
    for (int i = 0; i < 4; ++i) {
        int row = (t >> 4) + i * 16;
        int col = (t & 15) * 4;
        float4 v = *(const float4*)&xb[(size_t)(k0 + row) * HW_ + n0 + col];
        sm[row][col] = v.x; sm[row][col+1] = v.y; sm[row][col+2] = v.z; sm[row][col+3] = v.w;
    }
    __syncthreads();
    #pragma unroll
    for (int i = 0; i < 2; ++i) {
        int nl = (t >> 3) + i * 32;
        int ks = (t & 7) * 8;
        f16x8 h;
        #pragma unroll
        for (int j = 0; j < 8; ++j) h[j] = (_Float16)sm[ks + j][nl];
        *(f16x8*)&xtb[(size_t)(n0 + nl) * C_ + k0 + ks] = h;
    }
}

// ---------------- no-LDS MFMA GEMM: C[b] = W(M x 384) * XT[b](4096 x 384)^T ----------------
// 128x128 tile, 4 waves, frags loaded straight from global (L2-hot), no barriers.
// Operands swapped in the MFMA so D is pixel-major -> contiguous stores.
template<int M, bool F32OUT>
__global__ __launch_bounds__(256, 2) void mfma_gemm(
    const _Float16* __restrict__ Wb,
    const _Float16* __restrict__ XT,
    void* __restrict__ Cv, long long xstride, long long cstride)
{
    constexpr int K = 384;
    const int b  = blockIdx.z;
    const int m0 = blockIdx.y * 128;
    const int n0 = blockIdx.x * 128;
    const _Float16* __restrict__ XTb = XT + (size_t)b * xstride;
    const int t = threadIdx.x;
    const int l = t & 63, w = t >> 6;
    const int wr = w >> 1, wc = w & 1;
    const int frow = l & 15;
    const int kseg = (l >> 4) * 8;

    const _Float16* ap[4];
    const _Float16* bp[4];
    #pragma unroll
    for (int mi = 0; mi < 4; ++mi)
        ap[mi] = &Wb[(size_t)(m0 + wr * 64 + mi * 16 + frow) * K + kseg];
    #pragma unroll
    for (int ni = 0; ni < 4; ++ni)
        bp[ni] = &XTb[(size_t)(n0 + wc * 64 + ni * 16 + frow) * K + kseg];

    f32x4 acc[4][4] = {};
    #pragma unroll
    for (int ks = 0; ks < K / 32; ++ks) {
        f16x8 af[4], bf[4];
        #pragma unroll
        for (int mi = 0; mi < 4; ++mi) af[mi] = *(const f16x8*)(ap[mi] + ks * 32);
        #pragma unroll
        for (int ni = 0; ni < 4; ++ni) bf[ni] = *(const f16x8*)(bp[ni] + ks * 32);
        #pragma unroll
        for (int mi = 0; mi < 4; ++mi)
            #pragma unroll
            for (int ni = 0; ni < 4; ++ni)
                acc[mi][ni] = __builtin_amdgcn_mfma_f32_16x16x32_f16(
                    bf[ni], af[mi], acc[mi][ni], 0, 0, 0);   // D[pixel][channel]
    }
    // D layout: col = l&15 -> channel-within-16 ; row = (l>>4)*4 + r -> pixel-within-16
    const int pxl = (l >> 4) * 4;
    const int chl = l & 15;
    if constexpr (F32OUT) {
        float* Co = (float*)Cv + (size_t)b * cstride;
        #pragma unroll
        for (int mi = 0; mi < 4; ++mi)
            #pragma unroll
            for (int ni = 0; ni < 4; ++ni)
                *(f32x4*)&Co[(size_t)(m0 + wr * 64 + mi * 16 + chl) * HW_
                             + n0 + wc * 64 + ni * 16 + pxl] = acc[mi][ni];
    } else {
        _Float16* Co = (_Float16*)Cv + (size_t)b * cstride;
        #pragma unroll
        for (int mi = 0; mi < 4; ++mi)
            #pragma unroll
            for (int ni = 0; ni < 4; ++ni) {
                f16x4 h;
                #pragma unroll
                for (int r = 0; r < 4; ++r) h[r] = (_Float16)acc[mi][ni][r];
                *(f16x4*)&Co[(size_t)(m0 + wr * 64 + mi * 16 + chl) * HW_
                             + n0 + wc * 64 + ni * 16 + pxl] = h;
            }
    }
}

// ---------------- depthwise 3x3 SAME in-place (fp16) + fused q/k row-norms ----------------
__global__ __launch_bounds__(256) void dwconv_norm(
    _Float16* __restrict__ buf, const float* __restrict__ wdw,
    float* __restrict__ nqinv, float* __restrict__ nkinv)
{
    const int plane = blockIdx.x;           // b*1152 + ch
    const int ch = plane % C3_, b = plane / C3_;
    __shared__ float sm[64 * 64];
    __shared__ float wsum[4];
    _Float16* g = buf + (size_t)plane * HW_;
    const int t = threadIdx.x;
    #pragma unroll
    for (int i = 0; i < 2; ++i) {
        f16x8 v = *(const f16x8*)&g[t * 8 + i * 2048];
        #pragma unroll
        for (int j = 0; j < 8; ++j) sm[t * 8 + i * 2048 + j] = (float)v[j];
    }
    float w[9];
    #pragma unroll
    for (int j = 0; j < 9; ++j) w[j] = wdw[ch * 9 + j];
    __syncthreads();
    float ssq = 0.f;
    #pragma unroll
    for (int i = 0; i < 16; ++i) {
        const int idx = i * 256 + t;
        const int y = idx >> 6, x = idx & 63;
        float s = 0.f;
        #pragma unroll
        for (int ky = 0; ky < 3; ++ky) {
            const int yy = y + ky - 1;
            if (yy < 0 || yy > 63) continue;
            #pragma unroll
            for (int kx = 0; kx < 3; ++kx) {
                const int xx = x + kx - 1;
                if (xx < 0 || xx > 63) continue;
                s = fmaf(w[ky * 3 + kx], sm[yy * 64 + xx], s);
            }
        }
        g[idx] = (_Float16)s;
        ssq = fmaf(s, s, ssq);
    }
    if (ch < 2 * C_) {
        #pragma unroll
        for (int m = 1; m < 64; m <<= 1) ssq += __shfl_xor(ssq, m);
        if ((t & 63) == 0) wsum[t >> 6] = ssq;
        __syncthreads();
        if (t == 0) {
            float tot = wsum[0] + wsum[1] + wsum[2] + wsum[3];
            float inv = 1.f / fmaxf(sqrtf(tot), 1e-12f);
            (ch < C_ ? nqinv : nkinv)[b * C_ + (ch % C_)] = inv;
        }
    }
}

// ---------------- raw scores partials: sp[ks][bh][48][48] (fp16 in, fp32 math) ----------------
__global__ __launch_bounds__(256) void scores_partial(
    const _Float16* __restrict__ buf, float* __restrict__ sp)
{
    const int bh = blockIdx.x;
    const int ks = blockIdx.y;
    const int b = bh >> 3, h = bh & 7;
    const _Float16* qbase = buf + ((size_t)b * C3_ + (size_t)h * D_) * HW_;
    const _Float16* kbase = qbase + (size_t)C_ * HW_;
    __shared__ float qs[48][65];
    __shared__ float ksm[48][65];
    const int t = threadIdx.x;
    const int d0 = (t >> 4) * 3, e0 = (t & 15) * 3;
    float acc[3][3] = {{0.f}};
    for (int kc = ks * 512; kc < ks * 512 + 512; kc += 64) {
        #pragma unroll
        for (int i = 0; i < 3; ++i) {
            const int idx = i * 256 + t;       // 0..767 ; 384 8-elem units per matrix
            const int isK = idx >= 384;
            const int u = isK ? idx - 384 : idx;
            const int row = u >> 3, col = (u & 7) * 8;
            f16x8 v = *(const f16x8*)&(isK ? kbase : qbase)[(size_t)row * HW_ + kc + col];
            float* dst = isK ? &ksm[row][col] : &qs[row][col];
            #pragma unroll
            for (int j = 0; j < 8; ++j) dst[j] = (float)v[j];
        }
        __syncthreads();
        #pragma unroll 8
        for (int kk = 0; kk < 64; ++kk) {
            float q0 = qs[d0][kk], q1 = qs[d0+1][kk], q2 = qs[d0+2][kk];
            float k0 = ksm[e0][kk], k1 = ksm[e0+1][kk], k2 = ksm[e0+2][kk];
            acc[0][0] = fmaf(q0, k0, acc[0][0]); acc[0][1] = fmaf(q0, k1, acc[0][1]); acc[0][2] = fmaf(q0, k2, acc[0][2]);
            acc[1][0] = fmaf(q1, k0, acc[1][0]); acc[1][1] = fmaf(q1, k1, acc[1][1]); acc[1][2] = fmaf(q1, k2, acc[1][2]);
            acc[2][0] = fmaf(q2, k0, acc[2][0]); acc[2][1] = fmaf(q2, k1, acc[2][1]); acc[2][2] = fmaf(q2, k2, acc[2][2]);
        }
        __syncthreads();
    }
    float* out = sp + ((size_t)ks * 128 + bh) * (D_ * D_);
    #pragma unroll
    for (int i = 0; i < 3; ++i)
        #pragma unroll
        for (int j = 0; j < 3; ++j)
            out[(d0 + i) * D_ + e0 + j] = acc[i][j];
}

// ---------------- reduce partials, scale, softmax ----------------
__global__ __launch_bounds__(64) void softmax_k(
    const float* __restrict__ sp, const float* __restrict__ nqinv,
    const float* __restrict__ nkinv, const float* __restrict__ temp,
    float* __restrict__ attn)
{
    const int row = blockIdx.x;
    const int bh = row / D_, d = row % D_;
    const int h = bh & 7;
    const int e = threadIdx.x;
    float s = -INFINITY;
    if (e < D_) {
        float raw = 0.f;
        #pragma unroll
        for (int ks = 0; ks < 8; ++ks)
            raw += sp[((size_t)ks * 128 + bh) * (D_ * D_) + d * D_ + e];
        s = raw * nqinv[bh * D_ + d] * nkinv[bh * D_ + e] * temp[h];
    }
    float m = s;
    #pragma unroll
    for (int off = 1; off < 64; off <<= 1) m = fmaxf(m, __shfl_xor(m, off));
    float p = (e < D_) ? expf(s - m) : 0.f;
    float sum = p;
    #pragma unroll
    for (int off = 1; off < 64; off <<= 1) sum += __shfl_xor(sum, off);
    if (e < D_) attn[(size_t)bh * (D_ * D_) + d * D_ + e] = p / sum;
}

// ---------------- attn @ v -> fp16 transposed [pixel][384] into q-plane region ----------------
__global__ __launch_bounds__(256) void pv_kernel(
    _Float16* __restrict__ buf, const float* __restrict__ attn)
{
    const int b = blockIdx.z, h = blockIdx.y;
    const int p0 = blockIdx.x * 512 + threadIdx.x * 2;
    __shared__ float a4[48][48];
    const float* ab = attn + ((size_t)b * 8 + h) * (D_ * D_);
    for (int i = threadIdx.x; i < D_ * D_; i += 256) ((float*)a4)[i] = ab[i];
    __syncthreads();
    const _Float16* vbase = buf + ((size_t)b * C3_ + 2 * C_ + (size_t)h * D_) * HW_;
    float2 acc[48];
    #pragma unroll
    for (int d = 0; d < 48; ++d) { acc[d].x = 0.f; acc[d].y = 0.f; }
    #pragma unroll 1
    for (int e4 = 0; e4 < 12; ++e4) {
        float2 vv[4];
        #pragma unroll
        for (int j = 0; j < 4; ++j) {
            f16x2 h2 = *(const f16x2*)&vbase[(size_t)(e4 * 4 + j) * HW_ + p0];
            vv[j].x = (float)h2[0]; vv[j].y = (float)h2[1];
        }
        #pragma unroll
        for (int d = 0; d < 48; ++d) {
            float4 a = *(const float4*)&a4[d][e4 * 4];
            acc[d].x = fmaf(a.x, vv[0].x, fmaf(a.y, vv[1].x, fmaf(a.z, vv[2].x, fmaf(a.w, vv[3].x, acc[d].x))));
            acc[d].y = fmaf(a.x, vv[0].y, fmaf(a.y, vv[1].y, fmaf(a.z, vv[2].y, fmaf(a.w, vv[3].y, acc[d].y))));
        }
    }
    _Float16* xt2b = buf + (size_t)b * C3_ * HW_;   // q region, dead now
    #pragma unroll
    for (int px = 0; px < 2; ++px) {
        f16x8 tmp[6];
        #pragma unroll
        for (int d = 0; d < 48; ++d) tmp[d >> 3][d & 7] = (_Float16)(px ? acc[d].y : acc[d].x);
        f16x8* dst = (f16x8*)&xt2b[(size_t)(p0 + px) * C_ + h * D_];
        #pragma unroll
        for (int j = 0; j < 6; ++j) dst[j] = tmp[j];
    }
}

extern "C" void kernel_launch(void* const* d_in, const int* in_sizes, int n_in,
                              void* d_out, int out_size, void* d_ws, size_t ws_size,
                              hipStream_t stream)
{
    const float* x      = (const float*)d_in[0];
    const float* w_qkv  = (const float*)d_in[1];
    const float* w_dw   = (const float*)d_in[2];
    const float* w_proj = (const float*)d_in[3];
    const float* temp   = (const float*)d_in[4];
    float* out = (float*)d_out;

    _Float16* buf = (_Float16*)d_ws;                       // 16*1152*4096 halves
    float* nqinv = (float*)(buf + (size_t)B_ * C3_ * HW_); // 6144 f
    float* nkinv = nqinv + 6144;
    float* sp    = nkinv + 6144;                           // 8*128*2304 f
    float* attn  = sp + (size_t)8 * 128 * D_ * D_;         // 128*2304 f
    _Float16* wqkv_h  = (_Float16*)(attn + (size_t)128 * D_ * D_);
    _Float16* wproj_h = wqkv_h + (size_t)C3_ * C_;
    _Float16* xt1     = wproj_h + (size_t)C_ * C_;         // 16*4096*384 halves

    // 0) weight + input conversion
    conv_w_f16<<<(C3_ * C_ / 4 + 255) / 256, 256, 0, stream>>>(w_qkv, wqkv_h, C3_ * C_ / 4);
    conv_w_f16<<<(C_ * C_ / 4 + 255) / 256, 256, 0, stream>>>(w_proj, wproj_h, C_ * C_ / 4);
    transpose_to_f16<<<dim3(64, 6, 16), 256, 0, stream>>>(x, xt1);

    // 1) qkv = w_qkv @ x (fp16 MFMA, no-LDS, fp16 out)
    mfma_gemm<C3_, false><<<dim3(32, 9, 16), 256, 0, stream>>>(
        wqkv_h, xt1, buf, (long long)HW_ * C_, (long long)C3_ * HW_);

    // 2) depthwise 3x3 SAME in place + fused q/k row norms
    dwconv_norm<<<B_ * C3_, 256, 0, stream>>>(buf, w_dw, nqinv, nkinv);

    // 3) raw score partials (K split 8)
    scores_partial<<<dim3(128, 8), 256, 0, stream>>>(buf, sp);

    // 4) reduce + scale + softmax
    softmax_k<<<6144, 64, 0, stream>>>(sp, nqinv, nkinv, temp, attn);

    // 5) attn @ v -> fp16 transposed into q region
    pv_kernel<<<dim3(8, 8, 16), 256, 0, stream>>>(buf, attn);

    // 6) out = w_proj @ attn_out (fp32 out)
    mfma_gemm<C_, true><<<dim3(32, 3, 16), 256, 0, stream>>>(
        wproj_h, buf, out, (long long)C3_ * HW_, (long long)C_ * HW_);
}

// Round 4
// 364.639 us; speedup vs baseline: 1.4229x; 1.4229x over previous
//
#include <hip/hip_runtime.h>
#include <hip/hip_bf16.h>
#include <math.h>

#define B_   16
#define C_   384
#define C3_  1152
#define HW_  4096
#define NH_  8
#define D_   48

typedef _Float16 f16x8 __attribute__((ext_vector_type(8)));
typedef _Float16 f16x4 __attribute__((ext_vector_type(4)));
typedef _Float16 f16x2 __attribute__((ext_vector_type(2)));
typedef float    f32x4 __attribute__((ext_vector_type(4)));

// ---------------- fp32 -> fp16 weight conversion ----------------
__global__ __launch_bounds__(256) void conv_w_f16(
    const float* __restrict__ w, _Float16* __restrict__ wh, int n4)
{
    int i = blockIdx.x * 256 + threadIdx.x;
    if (i < n4) {
        float4 v = *(const float4*)&w[(size_t)i * 4];
        f16x4 h = { (_Float16)v.x, (_Float16)v.y, (_Float16)v.z, (_Float16)v.w };
        *(f16x4*)&wh[(size_t)i * 4] = h;
    }
}

// ---------------- x [b][384][4096] f32 -> xt [b][4096][384] fp16 ----------------
__global__ __launch_bounds__(256) void transpose_to_f16(
    const float* __restrict__ x, _Float16* __restrict__ xt)
{
    const int b  = blockIdx.z;
    const int k0 = blockIdx.y * 64;
    const int n0 = blockIdx.x * 64;
    __shared__ float sm[64][65];
    const float* xb = x + (size_t)b * C_ * HW_;
    _Float16* xtb = xt + (size_t)b * HW_ * C_;
    const int t = threadIdx.x;
    #pragma unroll
    for (int i = 0; i < 4; ++i) {
        int row = (t >> 4) + i * 16;
        int col = (t & 15) * 4;
        float4 v = *(const float4*)&xb[(size_t)(k0 + row) * HW_ + n0 + col];
        sm[row][col] = v.x; sm[row][col+1] = v.y; sm[row][col+2] = v.z; sm[row][col+3] = v.w;
    }
    __syncthreads();
    #pragma unroll
    for (int i = 0; i < 2; ++i) {
        int nl = (t >> 3) + i * 32;
        int ks = (t & 7) * 8;
        f16x8 h;
        #pragma unroll
        for (int j = 0; j < 8; ++j) h[j] = (_Float16)sm[ks + j][nl];
        *(f16x8*)&xtb[(size_t)(n0 + nl) * C_ + k0 + ks] = h;
    }
}

// ---------------- MFMA GEMM: C[b] = W(M x 384) * XT[b](4096 x 384)^T ----------------
// 128x128 tile, BK=32, 4 waves, double-buffered LDS with prefetch-before-compute,
// XOR seg-swizzle (both sides) for conflict-free ds_read_b128, XCD-chunked grid.
template<int M, bool F32OUT>
__global__ __launch_bounds__(256, 3) void mfma_gemm(
    const _Float16* __restrict__ Wb,
    const _Float16* __restrict__ XT,
    void* __restrict__ Cv, long long xstride, long long cstride)
{
    constexpr int K = 384;
    constexpr int NSTEP = K / 32;       // 12
    constexpr int MB = M / 128;         // 9 or 3
    __shared__ _Float16 As[2][128 * 32];
    __shared__ _Float16 Bs[2][128 * 32];

    // bijective XCD swizzle (nwg % 8 == 0); logical order: m fastest, then n, then b
    const int nwg = MB * 32 * B_;
    const int cpx = nwg >> 3;
    const int bid = blockIdx.x;
    const int L   = (bid & 7) * cpx + (bid >> 3);
    const int m0  = (L % MB) * 128;
    const int nb  = L / MB;
    const int n0  = (nb & 31) * 128;
    const int b   = nb >> 5;

    const _Float16* __restrict__ XTb = XT + (size_t)b * xstride;
    const int t = threadIdx.x;
    const int l = t & 63, w = t >> 6;
    const int wr = w >> 1, wc = w & 1;
    const int frow = l & 15, kseg16 = l >> 4;

    // staging: thread t -> LDS row t>>2 (+64 for 2nd half), 16B slot t&3 (linear dest).
    // global source pre-swizzled with the same involution the reader applies.
    const int srow0 = t >> 2;
    const int ssegA = ((t & 3) ^ ((srow0 >> 1) & 3)) * 8;   // (row>>1)&3 invariant to +64

    auto stage = [&](int d, int kt) {
        const int kk = kt * 32;
        #pragma unroll
        for (int i = 0; i < 2; ++i) {
            const int row = srow0 + i * 64;
            const _Float16* ga = Wb  + (size_t)(m0 + row) * K + kk + ssegA;
            const _Float16* gb = XTb + (size_t)(n0 + row) * K + kk + ssegA;
            __builtin_amdgcn_global_load_lds(
                (const __attribute__((address_space(1))) void*)ga,
                (__attribute__((address_space(3))) void*)((char*)&As[d][0] + w * 1024 + i * 4096),
                16, 0, 0);
            __builtin_amdgcn_global_load_lds(
                (const __attribute__((address_space(1))) void*)gb,
                (__attribute__((address_space(3))) void*)((char*)&Bs[d][0] + w * 1024 + i * 4096),
                16, 0, 0);
        }
    };

    f32x4 acc[4][4] = {};

    stage(0, 0);
    __syncthreads();                      // compiler drains vmcnt before barrier
    #pragma unroll 2
    for (int ksi = 0; ksi < NSTEP; ++ksi) {
        const int cur = ksi & 1;
        if (ksi + 1 < NSTEP) stage(cur ^ 1, ksi + 1);   // prefetch overlaps compute
        f16x8 af[4], bfr[4];
        #pragma unroll
        for (int mi = 0; mi < 4; ++mi) {
            const int rA = wr * 64 + mi * 16 + frow;
            af[mi] = *(const f16x8*)&As[cur][rA * 32 + ((kseg16 ^ ((rA >> 1) & 3)) << 3)];
        }
        #pragma unroll
        for (int ni = 0; ni < 4; ++ni) {
            const int rB = wc * 64 + ni * 16 + frow;
            bfr[ni] = *(const f16x8*)&Bs[cur][rB * 32 + ((kseg16 ^ ((rB >> 1) & 3)) << 3)];
        }
        #pragma unroll
        for (int mi = 0; mi < 4; ++mi)
            #pragma unroll
            for (int ni = 0; ni < 4; ++ni)
                acc[mi][ni] = __builtin_amdgcn_mfma_f32_16x16x32_f16(
                    bfr[ni], af[mi], acc[mi][ni], 0, 0, 0);   // D[pixel][channel]
        __syncthreads();
    }
    // D layout: col = l&15 -> channel-within-16 ; row = (l>>4)*4 + r -> pixel-within-16
    const int pxl = (l >> 4) * 4;
    const int chl = l & 15;
    if constexpr (F32OUT) {
        float* Co = (float*)Cv + (size_t)b * cstride;
        #pragma unroll
        for (int mi = 0; mi < 4; ++mi)
            #pragma unroll
            for (int ni = 0; ni < 4; ++ni)
                *(f32x4*)&Co[(size_t)(m0 + wr * 64 + mi * 16 + chl) * HW_
                             + n0 + wc * 64 + ni * 16 + pxl] = acc[mi][ni];
    } else {
        _Float16* Co = (_Float16*)Cv + (size_t)b * cstride;
        #pragma unroll
        for (int mi = 0; mi < 4; ++mi)
            #pragma unroll
            for (int ni = 0; ni < 4; ++ni) {
                f16x4 h;
                #pragma unroll
                for (int r = 0; r < 4; ++r) h[r] = (_Float16)acc[mi][ni][r];
                *(f16x4*)&Co[(size_t)(m0 + wr * 64 + mi * 16 + chl) * HW_
                             + n0 + wc * 64 + ni * 16 + pxl] = h;
            }
    }
}

// ---------------- depthwise 3x3 SAME in-place (fp16) + fused q/k row-norms ----------------
__global__ __launch_bounds__(256) void dwconv_norm(
    _Float16* __restrict__ buf, const float* __restrict__ wdw,
    float* __restrict__ nqinv, float* __restrict__ nkinv)
{
    const int plane = blockIdx.x;           // b*1152 + ch
    const int ch = plane % C3_, b = plane / C3_;
    __shared__ float sm[64 * 64];
    __shared__ float wsum[4];
    _Float16* g = buf + (size_t)plane * HW_;
    const int t = threadIdx.x;
    #pragma unroll
    for (int i = 0; i < 2; ++i) {
        f16x8 v = *(const f16x8*)&g[t * 8 + i * 2048];
        #pragma unroll
        for (int j = 0; j < 8; ++j) sm[t * 8 + i * 2048 + j] = (float)v[j];
    }
    float w[9];
    #pragma unroll
    for (int j = 0; j < 9; ++j) w[j] = wdw[ch * 9 + j];
    __syncthreads();
    float ssq = 0.f;
    #pragma unroll
    for (int i = 0; i < 16; ++i) {
        const int idx = i * 256 + t;
        const int y = idx >> 6, x = idx & 63;
        float s = 0.f;
        #pragma unroll
        for (int ky = 0; ky < 3; ++ky) {
            const int yy = y + ky - 1;
            if (yy < 0 || yy > 63) continue;
            #pragma unroll
            for (int kx = 0; kx < 3; ++kx) {
                const int xx = x + kx - 1;
                if (xx < 0 || xx > 63) continue;
                s = fmaf(w[ky * 3 + kx], sm[yy * 64 + xx], s);
            }
        }
        g[idx] = (_Float16)s;
        ssq = fmaf(s, s, ssq);
    }
    if (ch < 2 * C_) {
        #pragma unroll
        for (int m = 1; m < 64; m <<= 1) ssq += __shfl_xor(ssq, m);
        if ((t & 63) == 0) wsum[t >> 6] = ssq;
        __syncthreads();
        if (t == 0) {
            float tot = wsum[0] + wsum[1] + wsum[2] + wsum[3];
            float inv = 1.f / fmaxf(sqrtf(tot), 1e-12f);
            (ch < C_ ? nqinv : nkinv)[b * C_ + (ch % C_)] = inv;
        }
    }
}

// ---------------- raw scores partials: sp[ks][bh][48][48] (fp16 in, fp32 math) ----------------
__global__ __launch_bounds__(256) void scores_partial(
    const _Float16* __restrict__ buf, float* __restrict__ sp)
{
    const int bh = blockIdx.x;
    const int ks = blockIdx.y;
    const int b = bh >> 3, h = bh & 7;
    const _Float16* qbase = buf + ((size_t)b * C3_ + (size_t)h * D_) * HW_;
    const _Float16* kbase = qbase + (size_t)C_ * HW_;
    __shared__ float qs[48][65];
    __shared__ float ksm[48][65];
    const int t = threadIdx.x;
    const int d0 = (t >> 4) * 3, e0 = (t & 15) * 3;
    float acc[3][3] = {{0.f}};
    for (int kc = ks * 512; kc < ks * 512 + 512; kc += 64) {
        #pragma unroll
        for (int i = 0; i < 3; ++i) {
            const int idx = i * 256 + t;       // 0..767 ; 384 8-elem units per matrix
            const int isK = idx >= 384;
            const int u = isK ? idx - 384 : idx;
            const int row = u >> 3, col = (u & 7) * 8;
            f16x8 v = *(const f16x8*)&(isK ? kbase : qbase)[(size_t)row * HW_ + kc + col];
            float* dst = isK ? &ksm[row][col] : &qs[row][col];
            #pragma unroll
            for (int j = 0; j < 8; ++j) dst[j] = (float)v[j];
        }
        __syncthreads();
        #pragma unroll 8
        for (int kk = 0; kk < 64; ++kk) {
            float q0 = qs[d0][kk], q1 = qs[d0+1][kk], q2 = qs[d0+2][kk];
            float k0 = ksm[e0][kk], k1 = ksm[e0+1][kk], k2 = ksm[e0+2][kk];
            acc[0][0] = fmaf(q0, k0, acc[0][0]); acc[0][1] = fmaf(q0, k1, acc[0][1]); acc[0][2] = fmaf(q0, k2, acc[0][2]);
            acc[1][0] = fmaf(q1, k0, acc[1][0]); acc[1][1] = fmaf(q1, k1, acc[1][1]); acc[1][2] = fmaf(q1, k2, acc[1][2]);
            acc[2][0] = fmaf(q2, k0, acc[2][0]); acc[2][1] = fmaf(q2, k1, acc[2][1]); acc[2][2] = fmaf(q2, k2, acc[2][2]);
        }
        __syncthreads();
    }
    float* out = sp + ((size_t)ks * 128 + bh) * (D_ * D_);
    #pragma unroll
    for (int i = 0; i < 3; ++i)
        #pragma unroll
        for (int j = 0; j < 3; ++j)
            out[(d0 + i) * D_ + e0 + j] = acc[i][j];
}

// ---------------- reduce partials, scale, softmax ----------------
__global__ __launch_bounds__(64) void softmax_k(
    const float* __restrict__ sp, const float* __restrict__ nqinv,
    const float* __restrict__ nkinv, const float* __restrict__ temp,
    float* __restrict__ attn)
{
    const int row = blockIdx.x;
    const int bh = row / D_, d = row % D_;
    const int h = bh & 7;
    const int e = threadIdx.x;
    float s = -INFINITY;
    if (e < D_) {
        float raw = 0.f;
        #pragma unroll
        for (int ks = 0; ks < 8; ++ks)
            raw += sp[((size_t)ks * 128 + bh) * (D_ * D_) + d * D_ + e];
        s = raw * nqinv[bh * D_ + d] * nkinv[bh * D_ + e] * temp[h];
    }
    float m = s;
    #pragma unroll
    for (int off = 1; off < 64; off <<= 1) m = fmaxf(m, __shfl_xor(m, off));
    float p = (e < D_) ? expf(s - m) : 0.f;
    float sum = p;
    #pragma unroll
    for (int off = 1; off < 64; off <<= 1) sum += __shfl_xor(sum, off);
    if (e < D_) attn[(size_t)bh * (D_ * D_) + d * D_ + e] = p / sum;
}

// ---------------- attn @ v -> fp16 transposed [pixel][384] into q-plane region ----------------
__global__ __launch_bounds__(256) void pv_kernel(
    _Float16* __restrict__ buf, const float* __restrict__ attn)
{
    const int b = blockIdx.z, h = blockIdx.y;
    const int p0 = blockIdx.x * 512 + threadIdx.x * 2;
    __shared__ float a4[48][48];
    const float* ab = attn + ((size_t)b * 8 + h) * (D_ * D_);
    for (int i = threadIdx.x; i < D_ * D_; i += 256) ((float*)a4)[i] = ab[i];
    __syncthreads();
    const _Float16* vbase = buf + ((size_t)b * C3_ + 2 * C_ + (size_t)h * D_) * HW_;
    float2 acc[48];
    #pragma unroll
    for (int d = 0; d < 48; ++d) { acc[d].x = 0.f; acc[d].y = 0.f; }
    #pragma unroll 1
    for (int e4 = 0; e4 < 12; ++e4) {
        float2 vv[4];
        #pragma unroll
        for (int j = 0; j < 4; ++j) {
            f16x2 h2 = *(const f16x2*)&vbase[(size_t)(e4 * 4 + j) * HW_ + p0];
            vv[j].x = (float)h2[0]; vv[j].y = (float)h2[1];
        }
        #pragma unroll
        for (int d = 0; d < 48; ++d) {
            float4 a = *(const float4*)&a4[d][e4 * 4];
            acc[d].x = fmaf(a.x, vv[0].x, fmaf(a.y, vv[1].x, fmaf(a.z, vv[2].x, fmaf(a.w, vv[3].x, acc[d].x))));
            acc[d].y = fmaf(a.x, vv[0].y, fmaf(a.y, vv[1].y, fmaf(a.z, vv[2].y, fmaf(a.w, vv[3].y, acc[d].y))));
        }
    }
    _Float16* xt2b = buf + (size_t)b * C3_ * HW_;   // q region, dead now
    #pragma unroll
    for (int px = 0; px < 2; ++px) {
        f16x8 tmp[6];
        #pragma unroll
        for (int d = 0; d < 48; ++d) tmp[d >> 3][d & 7] = (_Float16)(px ? acc[d].y : acc[d].x);
        f16x8* dst = (f16x8*)&xt2b[(size_t)(p0 + px) * C_ + h * D_];
        #pragma unroll
        for (int j = 0; j < 6; ++j) dst[j] = tmp[j];
    }
}

extern "C" void kernel_launch(void* const* d_in, const int* in_sizes, int n_in,
                              void* d_out, int out_size, void* d_ws, size_t ws_size,
                              hipStream_t stream)
{
    const float* x      = (const float*)d_in[0];
    const float* w_qkv  = (const float*)d_in[1];
    const float* w_dw   = (const float*)d_in[2];
    const float* w_proj = (const float*)d_in[3];
    const float* temp   = (const float*)d_in[4];
    float* out = (float*)d_out;

    _Float16* buf = (_Float16*)d_ws;                       // 16*1152*4096 halves
    float* nqinv = (float*)(buf + (size_t)B_ * C3_ * HW_); // 6144 f
    float* nkinv = nqinv + 6144;
    float* sp    = nkinv + 6144;                           // 8*128*2304 f
    float* attn  = sp + (size_t)8 * 128 * D_ * D_;         // 128*2304 f
    _Float16* wqkv_h  = (_Float16*)(attn + (size_t)128 * D_ * D_);
    _Float16* wproj_h = wqkv_h + (size_t)C3_ * C_;
    _Float16* xt1     = wproj_h + (size_t)C_ * C_;         // 16*4096*384 halves

    // 0) weight + input conversion
    conv_w_f16<<<(C3_ * C_ / 4 + 255) / 256, 256, 0, stream>>>(w_qkv, wqkv_h, C3_ * C_ / 4);
    conv_w_f16<<<(C_ * C_ / 4 + 255) / 256, 256, 0, stream>>>(w_proj, wproj_h, C_ * C_ / 4);
    transpose_to_f16<<<dim3(64, 6, 16), 256, 0, stream>>>(x, xt1);

    // 1) qkv = w_qkv @ x (fp16 MFMA, dbuf+prefetch+swizzle, fp16 out)
    mfma_gemm<C3_, false><<<dim3(9 * 32 * 16), 256, 0, stream>>>(
        wqkv_h, xt1, buf, (long long)HW_ * C_, (long long)C3_ * HW_);

    // 2) depthwise 3x3 SAME in place + fused q/k row norms
    dwconv_norm<<<B_ * C3_, 256, 0, stream>>>(buf, w_dw, nqinv, nkinv);

    // 3) raw score partials (K split 8)
    scores_partial<<<dim3(128, 8), 256, 0, stream>>>(buf, sp);

    // 4) reduce + scale + softmax
    softmax_k<<<6144, 64, 0, stream>>>(sp, nqinv, nkinv, temp, attn);

    // 5) attn @ v -> fp16 transposed into q region
    pv_kernel<<<dim3(8, 8, 16), 256, 0, stream>>>(buf, attn);

    // 6) out = w_proj @ attn_out (fp32 out)
    mfma_gemm<C_, true><<<dim3(3 * 32 * 16), 256, 0, stream>>>(
        wproj_h, buf, out, (long long)C3_ * HW_, (long long)C_ * HW_);
}

// Round 5
// 328.044 us; speedup vs baseline: 1.5817x; 1.1116x over previous
//
#include <hip/hip_runtime.h>
#include <hip/hip_bf16.h>
#include <math.h>

#define B_   16
#define C_   384
#define C3_  1152
#define HW_  4096
#define NH_  8
#define D_   48

typedef _Float16 f16x8 __attribute__((ext_vector_type(8)));
typedef _Float16 f16x4 __attribute__((ext_vector_type(4)));
typedef _Float16 f16x2 __attribute__((ext_vector_type(2)));
typedef float    f32x4 __attribute__((ext_vector_type(4)));

#define STR_(x) #x
#define ASM_VMCNT(n) asm volatile("s_waitcnt vmcnt(" STR_(n) ")" ::: "memory")

// ---------------- fp32 -> fp16 weight conversion ----------------
__global__ __launch_bounds__(256) void conv_w_f16(
    const float* __restrict__ w, _Float16* __restrict__ wh, int n4)
{
    int i = blockIdx.x * 256 + threadIdx.x;
    if (i < n4) {
        float4 v = *(const float4*)&w[(size_t)i * 4];
        f16x4 h = { (_Float16)v.x, (_Float16)v.y, (_Float16)v.z, (_Float16)v.w };
        *(f16x4*)&wh[(size_t)i * 4] = h;
    }
}

// ---------------- x [b][384][4096] f32 -> xt [b][4096][384] fp16 ----------------
__global__ __launch_bounds__(256) void transpose_to_f16(
    const float* __restrict__ x, _Float16* __restrict__ xt)
{
    const int b  = blockIdx.z;
    const int k0 = blockIdx.y * 64;
    const int n0 = blockIdx.x * 64;
    __shared__ float sm[64][65];
    const float* xb = x + (size_t)b * C_ * HW_;
    _Float16* xtb = xt + (size_t)b * HW_ * C_;
    const int t = threadIdx.x;
    #pragma unroll
    for (int i = 0; i < 4; ++i) {
        int row = (t >> 4) + i * 16;
        int col = (t & 15) * 4;
        float4 v = *(const float4*)&xb[(size_t)(k0 + row) * HW_ + n0 + col];
        sm[row][col] = v.x; sm[row][col+1] = v.y; sm[row][col+2] = v.z; sm[row][col+3] = v.w;
    }
    __syncthreads();
    #pragma unroll
    for (int i = 0; i < 2; ++i) {
        int nl = (t >> 3) + i * 32;
        int ks = (t & 7) * 8;
        f16x8 h;
        #pragma unroll
        for (int j = 0; j < 8; ++j) h[j] = (_Float16)sm[ks + j][nl];
        *(f16x8*)&xtb[(size_t)(n0 + nl) * C_ + k0 + ks] = h;
    }
}

// ---------------- MFMA GEMM: C[b] = W(M x 384) * XT[b](4096 x 384)^T ----------------
// 128x128 tile, BK=64, 2 LDS buffers, depth-2 prefetch with COUNTED vmcnt (never
// drained in-loop), raw s_barrier pairs, 8-slot XOR swizzle both-sides, XCD-chunked.
template<int M, bool F32OUT>
__global__ __launch_bounds__(256, 2) void mfma_gemm(
    const _Float16* __restrict__ Wb,
    const _Float16* __restrict__ XT,
    void* __restrict__ Cv, long long xstride, long long cstride)
{
    constexpr int K = 384;
    constexpr int BK = 64;
    constexpr int NSTEP = K / BK;       // 6
    constexpr int MB = M / 128;         // 9 or 3
    __shared__ _Float16 As[2][128 * BK];
    __shared__ _Float16 Bs[2][128 * BK];

    // bijective XCD swizzle (nwg % 8 == 0); logical order: m fastest, then n, then b
    const int nwg = MB * 32 * B_;
    const int cpx = nwg >> 3;
    const int bid = blockIdx.x;
    const int L   = (bid & 7) * cpx + (bid >> 3);
    const int m0  = (L % MB) * 128;
    const int nb  = L / MB;
    const int n0  = (nb & 31) * 128;
    const int b   = nb >> 5;

    const _Float16* __restrict__ XTb = XT + (size_t)b * xstride;
    const int t = threadIdx.x;
    const int l = t & 63, w = t >> 6;
    const int wr = w >> 1, wc = w & 1;
    const int frow = l & 15, kseg16 = l >> 4;   // 0..3

    // staging: linear LDS dest (row = i*32 + t>>3, 16B slot = t&7);
    // global SOURCE pre-swizzled with the same involution the reader applies.
    const int srow  = t >> 3;
    const int sslot = t & 7;

    auto stage = [&](int d, int kt) {
        const int kk = kt * BK;
        #pragma unroll
        for (int i = 0; i < 4; ++i) {
            const int row  = i * 32 + srow;
            const int scol = (sslot ^ (row & 7)) * 8;
            const _Float16* ga = Wb  + (size_t)(m0 + row) * K + kk + scol;
            const _Float16* gb = XTb + (size_t)(n0 + row) * K + kk + scol;
            __builtin_amdgcn_global_load_lds(
                (const __attribute__((address_space(1))) void*)ga,
                (__attribute__((address_space(3))) void*)((char*)&As[d][0] + i * 4096 + t * 16),
                16, 0, 0);
            __builtin_amdgcn_global_load_lds(
                (const __attribute__((address_space(1))) void*)gb,
                (__attribute__((address_space(3))) void*)((char*)&Bs[d][0] + i * 4096 + t * 16),
                16, 0, 0);
        }
    };

    f32x4 acc[4][4] = {};

    stage(0, 0);          // 8 loads
    stage(1, 1);          // 8 loads -> 16 outstanding
    #pragma unroll
    for (int kt = 0; kt < NSTEP; ++kt) {
        const int cur = kt & 1;
        if (kt + 1 < NSTEP) { ASM_VMCNT(8); } else { ASM_VMCNT(0); }   // tile kt landed
        __builtin_amdgcn_sched_barrier(0);
        __builtin_amdgcn_s_barrier();          // all waves' tile-kt loads visible
        __builtin_amdgcn_sched_barrier(0);
        #pragma unroll
        for (int sub = 0; sub < 2; ++sub) {
            f16x8 af[4], bfr[4];
            #pragma unroll
            for (int mi = 0; mi < 4; ++mi) {
                const int rA = wr * 64 + mi * 16 + frow;
                const int cs = (sub * 4 + kseg16) ^ (rA & 7);
                af[mi] = *(const f16x8*)&As[cur][rA * BK + cs * 8];
            }
            #pragma unroll
            for (int ni = 0; ni < 4; ++ni) {
                const int rB = wc * 64 + ni * 16 + frow;
                const int cs = (sub * 4 + kseg16) ^ (rB & 7);
                bfr[ni] = *(const f16x8*)&Bs[cur][rB * BK + cs * 8];
            }
            __builtin_amdgcn_s_setprio(1);
            #pragma unroll
            for (int mi = 0; mi < 4; ++mi)
                #pragma unroll
                for (int ni = 0; ni < 4; ++ni)
                    acc[mi][ni] = __builtin_amdgcn_mfma_f32_16x16x32_f16(
                        bfr[ni], af[mi], acc[mi][ni], 0, 0, 0);   // D[pixel][channel]
            __builtin_amdgcn_s_setprio(0);
        }
        asm volatile("s_waitcnt lgkmcnt(0)" ::: "memory");
        __builtin_amdgcn_sched_barrier(0);
        __builtin_amdgcn_s_barrier();          // all waves done reading buf[cur]
        if (kt + 2 < NSTEP) stage(cur, kt + 2);
    }
    // D layout: col = l&15 -> channel-within-16 ; row = (l>>4)*4 + r -> pixel-within-16
    const int pxl = (l >> 4) * 4;
    const int chl = l & 15;
    if constexpr (F32OUT) {
        float* Co = (float*)Cv + (size_t)b * cstride;
        #pragma unroll
        for (int mi = 0; mi < 4; ++mi)
            #pragma unroll
            for (int ni = 0; ni < 4; ++ni)
                *(f32x4*)&Co[(size_t)(m0 + wr * 64 + mi * 16 + chl) * HW_
                             + n0 + wc * 64 + ni * 16 + pxl] = acc[mi][ni];
    } else {
        _Float16* Co = (_Float16*)Cv + (size_t)b * cstride;
        #pragma unroll
        for (int mi = 0; mi < 4; ++mi)
            #pragma unroll
            for (int ni = 0; ni < 4; ++ni) {
                f16x4 h;
                #pragma unroll
                for (int r = 0; r < 4; ++r) h[r] = (_Float16)acc[mi][ni][r];
                *(f16x4*)&Co[(size_t)(m0 + wr * 64 + mi * 16 + chl) * HW_
                             + n0 + wc * 64 + ni * 16 + pxl] = h;
            }
    }
}

// ---------------- depthwise 3x3 SAME in-place (fp16) + fused q/k row-norms ----------------
__global__ __launch_bounds__(256) void dwconv_norm(
    _Float16* __restrict__ buf, const float* __restrict__ wdw,
    float* __restrict__ nqinv, float* __restrict__ nkinv)
{
    const int plane = blockIdx.x;           // b*1152 + ch
    const int ch = plane % C3_, b = plane / C3_;
    __shared__ float sm[64 * 64];
    __shared__ float wsum[4];
    _Float16* g = buf + (size_t)plane * HW_;
    const int t = threadIdx.x;
    #pragma unroll
    for (int i = 0; i < 2; ++i) {
        f16x8 v = *(const f16x8*)&g[t * 8 + i * 2048];
        #pragma unroll
        for (int j = 0; j < 8; ++j) sm[t * 8 + i * 2048 + j] = (float)v[j];
    }
    float w[9];
    #pragma unroll
    for (int j = 0; j < 9; ++j) w[j] = wdw[ch * 9 + j];
    __syncthreads();
    float ssq = 0.f;
    #pragma unroll
    for (int i = 0; i < 16; ++i) {
        const int idx = i * 256 + t;
        const int y = idx >> 6, x = idx & 63;
        float s = 0.f;
        #pragma unroll
        for (int ky = 0; ky < 3; ++ky) {
            const int yy = y + ky - 1;
            if (yy < 0 || yy > 63) continue;
            #pragma unroll
            for (int kx = 0; kx < 3; ++kx) {
                const int xx = x + kx - 1;
                if (xx < 0 || xx > 63) continue;
                s = fmaf(w[ky * 3 + kx], sm[yy * 64 + xx], s);
            }
        }
        g[idx] = (_Float16)s;
        ssq = fmaf(s, s, ssq);
    }
    if (ch < 2 * C_) {
        #pragma unroll
        for (int m = 1; m < 64; m <<= 1) ssq += __shfl_xor(ssq, m);
        if ((t & 63) == 0) wsum[t >> 6] = ssq;
        __syncthreads();
        if (t == 0) {
            float tot = wsum[0] + wsum[1] + wsum[2] + wsum[3];
            float inv = 1.f / fmaxf(sqrtf(tot), 1e-12f);
            (ch < C_ ? nqinv : nkinv)[b * C_ + (ch % C_)] = inv;
        }
    }
}

// ---------------- MFMA scores: sp[ks][bh][48][48], ksplit=4, 4 waves/block ----------------
__global__ __launch_bounds__(256) void scores_mfma(
    const _Float16* __restrict__ buf, float* __restrict__ sp)
{
    const int bh = blockIdx.x;              // 0..127
    const int ks = blockIdx.y;              // 0..3
    const int b = bh >> 3, h = bh & 7;
    const _Float16* qbase = buf + ((size_t)b * C3_ + (size_t)h * D_) * HW_;
    const _Float16* kbase = qbase + (size_t)C_ * HW_;
    const int t = threadIdx.x, l = t & 63, w = t >> 6;
    const int frow = l & 15, kseg = (l >> 4) * 8;
    const int p0 = ks * 1024 + w * 256;     // this wave's 256-pixel slice

    f32x4 acc[3][3] = {};
    #pragma unroll 2
    for (int st = 0; st < 8; ++st) {
        const int p = p0 + st * 32 + kseg;
        f16x8 qf[3], kf[3];
        #pragma unroll
        for (int mi = 0; mi < 3; ++mi)
            qf[mi] = *(const f16x8*)&qbase[(size_t)(mi * 16 + frow) * HW_ + p];
        #pragma unroll
        for (int ni = 0; ni < 3; ++ni)
            kf[ni] = *(const f16x8*)&kbase[(size_t)(ni * 16 + frow) * HW_ + p];
        #pragma unroll
        for (int mi = 0; mi < 3; ++mi)
            #pragma unroll
            for (int ni = 0; ni < 3; ++ni)
                acc[mi][ni] = __builtin_amdgcn_mfma_f32_16x16x32_f16(
                    qf[mi], kf[ni], acc[mi][ni], 0, 0, 0);   // D[d][e]
    }
    // cross-wave reduce in LDS
    __shared__ float red[4][D_ * D_];
    #pragma unroll
    for (int mi = 0; mi < 3; ++mi)
        #pragma unroll
        for (int ni = 0; ni < 3; ++ni)
            #pragma unroll
            for (int r = 0; r < 4; ++r)
                red[w][(mi * 16 + (l >> 4) * 4 + r) * D_ + ni * 16 + (l & 15)] =
                    acc[mi][ni][r];
    __syncthreads();
    float* out = sp + ((size_t)ks * 128 + bh) * (D_ * D_);
    const float* rf = &red[0][0];
    for (int i = t; i < D_ * D_; i += 256)
        out[i] = rf[i] + rf[2304 + i] + rf[4608 + i] + rf[6912 + i];
}

// ---------------- reduce partials, scale, softmax ----------------
__global__ __launch_bounds__(64) void softmax_k(
    const float* __restrict__ sp, const float* __restrict__ nqinv,
    const float* __restrict__ nkinv, const float* __restrict__ temp,
    float* __restrict__ attn)
{
    const int row = blockIdx.x;
    const int bh = row / D_, d = row % D_;
    const int h = bh & 7;
    const int e = threadIdx.x;
    float s = -INFINITY;
    if (e < D_) {
        float raw = 0.f;
        #pragma unroll
        for (int ks = 0; ks < 4; ++ks)
            raw += sp[((size_t)ks * 128 + bh) * (D_ * D_) + d * D_ + e];
        s = raw * nqinv[bh * D_ + d] * nkinv[bh * D_ + e] * temp[h];
    }
    float m = s;
    #pragma unroll
    for (int off = 1; off < 64; off <<= 1) m = fmaxf(m, __shfl_xor(m, off));
    float p = (e < D_) ? expf(s - m) : 0.f;
    float sum = p;
    #pragma unroll
    for (int off = 1; off < 64; off <<= 1) sum += __shfl_xor(sum, off);
    if (e < D_) attn[(size_t)bh * (D_ * D_) + d * D_ + e] = p / sum;
}

// ---------------- attn @ v -> fp16 transposed [pixel][384] into q-plane region ----------------
__global__ __launch_bounds__(256) void pv_kernel(
    _Float16* __restrict__ buf, const float* __restrict__ attn)
{
    const int b = blockIdx.z, h = blockIdx.y;
    const int p0 = blockIdx.x * 512 + threadIdx.x * 2;
    __shared__ float a4[48][48];
    const float* ab = attn + ((size_t)b * 8 + h) * (D_ * D_);
    for (int i = threadIdx.x; i < D_ * D_; i += 256) ((float*)a4)[i] = ab[i];
    __syncthreads();
    const _Float16* vbase = buf + ((size_t)b * C3_ + 2 * C_ + (size_t)h * D_) * HW_;
    float2 acc[48];
    #pragma unroll
    for (int d = 0; d < 48; ++d) { acc[d].x = 0.f; acc[d].y = 0.f; }
    #pragma unroll 1
    for (int e4 = 0; e4 < 12; ++e4) {
        float2 vv[4];
        #pragma unroll
        for (int j = 0; j < 4; ++j) {
            f16x2 h2 = *(const f16x2*)&vbase[(size_t)(e4 * 4 + j) * HW_ + p0];
            vv[j].x = (float)h2[0]; vv[j].y = (float)h2[1];
        }
        #pragma unroll
        for (int d = 0; d < 48; ++d) {
            float4 a = *(const float4*)&a4[d][e4 * 4];
            acc[d].x = fmaf(a.x, vv[0].x, fmaf(a.y, vv[1].x, fmaf(a.z, vv[2].x, fmaf(a.w, vv[3].x, acc[d].x))));
            acc[d].y = fmaf(a.x, vv[0].y, fmaf(a.y, vv[1].y, fmaf(a.z, vv[2].y, fmaf(a.w, vv[3].y, acc[d].y))));
        }
    }
    _Float16* xt2b = buf + (size_t)b * C3_ * HW_;   // q region, dead now
    #pragma unroll
    for (int px = 0; px < 2; ++px) {
        f16x8 tmp[6];
        #pragma unroll
        for (int d = 0; d < 48; ++d) tmp[d >> 3][d & 7] = (_Float16)(px ? acc[d].y : acc[d].x);
        f16x8* dst = (f16x8*)&xt2b[(size_t)(p0 + px) * C_ + h * D_];
        #pragma unroll
        for (int j = 0; j < 6; ++j) dst[j] = tmp[j];
    }
}

extern "C" void kernel_launch(void* const* d_in, const int* in_sizes, int n_in,
                              void* d_out, int out_size, void* d_ws, size_t ws_size,
                              hipStream_t stream)
{
    const float* x      = (const float*)d_in[0];
    const float* w_qkv  = (const float*)d_in[1];
    const float* w_dw   = (const float*)d_in[2];
    const float* w_proj = (const float*)d_in[3];
    const float* temp   = (const float*)d_in[4];
    float* out = (float*)d_out;

    _Float16* buf = (_Float16*)d_ws;                       // 16*1152*4096 halves
    float* nqinv = (float*)(buf + (size_t)B_ * C3_ * HW_); // 6144 f
    float* nkinv = nqinv + 6144;
    float* sp    = nkinv + 6144;                           // 4*128*2304 f
    float* attn  = sp + (size_t)4 * 128 * D_ * D_;         // 128*2304 f
    _Float16* wqkv_h  = (_Float16*)(attn + (size_t)128 * D_ * D_);
    _Float16* wproj_h = wqkv_h + (size_t)C3_ * C_;
    _Float16* xt1     = wproj_h + (size_t)C_ * C_;         // 16*4096*384 halves

    // 0) weight + input conversion
    conv_w_f16<<<(C3_ * C_ / 4 + 255) / 256, 256, 0, stream>>>(w_qkv, wqkv_h, C3_ * C_ / 4);
    conv_w_f16<<<(C_ * C_ / 4 + 255) / 256, 256, 0, stream>>>(w_proj, wproj_h, C_ * C_ / 4);
    transpose_to_f16<<<dim3(64, 6, 16), 256, 0, stream>>>(x, xt1);

    // 1) qkv = w_qkv @ x (fp16 MFMA, counted-vmcnt pipeline, fp16 out)
    mfma_gemm<C3_, false><<<dim3(9 * 32 * 16), 256, 0, stream>>>(
        wqkv_h, xt1, buf, (long long)HW_ * C_, (long long)C3_ * HW_);

    // 2) depthwise 3x3 SAME in place + fused q/k row norms
    dwconv_norm<<<B_ * C3_, 256, 0, stream>>>(buf, w_dw, nqinv, nkinv);

    // 3) raw score partials via MFMA (K split 4)
    scores_mfma<<<dim3(128, 4), 256, 0, stream>>>(buf, sp);

    // 4) reduce + scale + softmax
    softmax_k<<<6144, 64, 0, stream>>>(sp, nqinv, nkinv, temp, attn);

    // 5) attn @ v -> fp16 transposed into q region
    pv_kernel<<<dim3(8, 8, 16), 256, 0, stream>>>(buf, attn);

    // 6) out = w_proj @ attn_out (fp32 out)
    mfma_gemm<C_, true><<<dim3(3 * 32 * 16), 256, 0, stream>>>(
        wproj_h, buf, out, (long long)C3_ * HW_, (long long)C_ * HW_);
}

// Round 6
// 296.571 us; speedup vs baseline: 1.7495x; 1.1061x over previous
//
#include <hip/hip_runtime.h>
#include <hip/hip_bf16.h>
#include <math.h>

#define B_   16
#define C_   384
#define C3_  1152
#define HW_  4096
#define NH_  8
#define D_   48

typedef _Float16 f16x8 __attribute__((ext_vector_type(8)));
typedef _Float16 f16x4 __attribute__((ext_vector_type(4)));
typedef _Float16 f16x2 __attribute__((ext_vector_type(2)));
typedef float    f32x4 __attribute__((ext_vector_type(4)));

#define ASM_VMCNT(n) asm volatile("s_waitcnt vmcnt(" #n ")" ::: "memory")

// ---------------- fp32 -> fp16 weight conversion ----------------
__global__ __launch_bounds__(256) void conv_w_f16(
    const float* __restrict__ w, _Float16* __restrict__ wh, int n4)
{
    int i = blockIdx.x * 256 + threadIdx.x;
    if (i < n4) {
        float4 v = *(const float4*)&w[(size_t)i * 4];
        f16x4 h = { (_Float16)v.x, (_Float16)v.y, (_Float16)v.z, (_Float16)v.w };
        *(f16x4*)&wh[(size_t)i * 4] = h;
    }
}

// ---------------- x [b][384][4096] f32 -> xt [b][4096][384] fp16 ----------------
__global__ __launch_bounds__(256) void transpose_to_f16(
    const float* __restrict__ x, _Float16* __restrict__ xt)
{
    const int b  = blockIdx.z;
    const int k0 = blockIdx.y * 64;
    const int n0 = blockIdx.x * 64;
    __shared__ float sm[64][65];
    const float* xb = x + (size_t)b * C_ * HW_;
    _Float16* xtb = xt + (size_t)b * HW_ * C_;
    const int t = threadIdx.x;
    #pragma unroll
    for (int i = 0; i < 4; ++i) {
        int row = (t >> 4) + i * 16;
        int col = (t & 15) * 4;
        float4 v = *(const float4*)&xb[(size_t)(k0 + row) * HW_ + n0 + col];
        sm[row][col] = v.x; sm[row][col+1] = v.y; sm[row][col+2] = v.z; sm[row][col+3] = v.w;
    }
    __syncthreads();
    #pragma unroll
    for (int i = 0; i < 2; ++i) {
        int nl = (t >> 3) + i * 32;
        int ks = (t & 7) * 8;
        f16x8 h;
        #pragma unroll
        for (int j = 0; j < 8; ++j) h[j] = (_Float16)sm[ks + j][nl];
        *(f16x8*)&xtb[(size_t)(n0 + nl) * C_ + k0 + ks] = h;
    }
}

// ---------------- MFMA GEMM: C[b] = W(M x 384) * XT[b](4096 x 384)^T ----------------
// 128x256 block tile, wave-tile 128x64 (4 waves n-split), BK=32, 3 LDS buffers,
// depth-3 prefetch with counted vmcnt, conflict-free XOR swizzle (both sides).
template<int M, bool F32OUT>
__global__ __launch_bounds__(256, 2) void mfma_gemm(
    const _Float16* __restrict__ Wb,
    const _Float16* __restrict__ XT,
    void* __restrict__ Cv, long long xstride, long long cstride)
{
    constexpr int K = 384;
    constexpr int BK = 32;
    constexpr int NSTEP = K / BK;            // 12
    constexpr int MB = M / 128;              // 9 or 3
    __shared__ _Float16 lds[3][(128 + 256) * BK];   // A (128x32) then B (256x32)

    // bijective XCD swizzle; logical order: m fastest, then n, then b
    const int nwg = MB * 16 * B_;
    const int cpx = nwg >> 3;
    const int bid = blockIdx.x;
    const int L   = (bid & 7) * cpx + (bid >> 3);
    const int m0  = (L % MB) * 128;
    const int nb  = L / MB;
    const int n0  = (nb & 15) * 256;
    const int b   = nb >> 4;

    const _Float16* __restrict__ XTb = XT + (size_t)b * xstride;
    const int t = threadIdx.x;
    const int l = t & 63, w = t >> 6;
    const int frow = l & 15, kseg16 = l >> 4;    // 0..3

    auto stage = [&](int d, int kt) {
        const int kk = kt * BK;
        #pragma unroll
        for (int i = 0; i < 2; ++i) {            // A: 128 rows x 32 k
            const int u = i * 256 + t;
            const int row = u >> 2, slot = u & 3;
            const int scol = slot ^ (row & 3) ^ ((row >> 2) & 1);
            const _Float16* ga = Wb + (size_t)(m0 + row) * K + kk + scol * 8;
            __builtin_amdgcn_global_load_lds(
                (const __attribute__((address_space(1))) void*)ga,
                (__attribute__((address_space(3))) void*)((char*)&lds[d][0] + u * 16),
                16, 0, 0);
        }
        #pragma unroll
        for (int i = 0; i < 4; ++i) {            // B: 256 rows x 32 k
            const int u = i * 256 + t;
            const int row = u >> 2, slot = u & 3;
            const int scol = slot ^ (row & 3) ^ ((row >> 2) & 1);
            const _Float16* gb = XTb + (size_t)(n0 + row) * K + kk + scol * 8;
            __builtin_amdgcn_global_load_lds(
                (const __attribute__((address_space(1))) void*)gb,
                (__attribute__((address_space(3))) void*)((char*)&lds[d][0] + 8192 + u * 16),
                16, 0, 0);
        }
    };

    f32x4 acc[8][4] = {};

    stage(0, 0); stage(1, 1); stage(2, 2);       // 18 loads outstanding
    #pragma unroll
    for (int kt = 0; kt < NSTEP; ++kt) {
        const int cur = kt % 3;
        if (kt <= 9)       { ASM_VMCNT(12); }    // oldest stage (tile kt) landed
        else if (kt == 10) { ASM_VMCNT(6); }
        else               { ASM_VMCNT(0); }
        __builtin_amdgcn_sched_barrier(0);
        __builtin_amdgcn_s_barrier();
        __builtin_amdgcn_sched_barrier(0);
        f16x8 af[8], bfr[4];
        #pragma unroll
        for (int mi = 0; mi < 8; ++mi) {
            const int rA = mi * 16 + frow;
            const int cs = kseg16 ^ (rA & 3) ^ ((rA >> 2) & 1);
            af[mi] = *(const f16x8*)&lds[cur][rA * 32 + cs * 8];
        }
        #pragma unroll
        for (int ni = 0; ni < 4; ++ni) {
            const int rB = w * 64 + ni * 16 + frow;
            const int cs = kseg16 ^ (rB & 3) ^ ((rB >> 2) & 1);
            bfr[ni] = *(const f16x8*)&lds[cur][4096 + rB * 32 + cs * 8];
        }
        __builtin_amdgcn_s_setprio(1);
        #pragma unroll
        for (int mi = 0; mi < 8; ++mi)
            #pragma unroll
            for (int ni = 0; ni < 4; ++ni)
                acc[mi][ni] = __builtin_amdgcn_mfma_f32_16x16x32_f16(
                    bfr[ni], af[mi], acc[mi][ni], 0, 0, 0);   // D[pixel][channel]
        __builtin_amdgcn_s_setprio(0);
        asm volatile("s_waitcnt lgkmcnt(0)" ::: "memory");
        __builtin_amdgcn_sched_barrier(0);
        __builtin_amdgcn_s_barrier();            // all waves done reading buf[cur]
        if (kt + 3 < NSTEP) stage(cur, kt + 3);
    }
    // D layout: col = l&15 -> channel-within-16 ; row = (l>>4)*4 + r -> pixel-within-16
    const int pxl = (l >> 4) * 4;
    const int chl = l & 15;
    if constexpr (F32OUT) {
        float* Co = (float*)Cv + (size_t)b * cstride;
        #pragma unroll
        for (int mi = 0; mi < 8; ++mi)
            #pragma unroll
            for (int ni = 0; ni < 4; ++ni)
                *(f32x4*)&Co[(size_t)(m0 + mi * 16 + chl) * HW_
                             + n0 + w * 64 + ni * 16 + pxl] = acc[mi][ni];
    } else {
        _Float16* Co = (_Float16*)Cv + (size_t)b * cstride;
        #pragma unroll
        for (int mi = 0; mi < 8; ++mi)
            #pragma unroll
            for (int ni = 0; ni < 4; ++ni) {
                f16x4 h;
                #pragma unroll
                for (int r = 0; r < 4; ++r) h[r] = (_Float16)acc[mi][ni][r];
                *(f16x4*)&Co[(size_t)(m0 + mi * 16 + chl) * HW_
                             + n0 + w * 64 + ni * 16 + pxl] = h;
            }
    }
}

// ---------------- depthwise 3x3 SAME in-place (fp16) + fused q/k row-norms ----------------
// fp16 LDS with stride-72 rows: 16B-aligned, conflict-free b128; 12 LDS reads / 8 px.
__global__ __launch_bounds__(256) void dwconv_norm(
    _Float16* __restrict__ buf, const float* __restrict__ wdw,
    float* __restrict__ nqinv, float* __restrict__ nkinv)
{
    const int plane = blockIdx.x;           // b*1152 + ch
    const int ch = plane % C3_, b = plane / C3_;
    __shared__ _Float16 smh[64 * 72];
    __shared__ float wsum[4];
    _Float16* g = buf + (size_t)plane * HW_;
    const int t = threadIdx.x;
    #pragma unroll
    for (int i = 0; i < 2; ++i) {
        const int u = i * 256 + t;          // row u>>3, col (u&7)*8
        f16x8 v = *(const f16x8*)&g[u * 8];
        *(f16x8*)&smh[(u >> 3) * 72 + (u & 7) * 8] = v;
    }
    float w[9];
    #pragma unroll
    for (int j = 0; j < 9; ++j) w[j] = wdw[ch * 9 + j];
    __syncthreads();
    float ssq = 0.f;
    #pragma unroll
    for (int i = 0; i < 2; ++i) {
        const int u = i * 256 + t;
        const int y = u >> 3, c0 = (u & 7) * 8;
        float r[3][10];
        #pragma unroll
        for (int dy = 0; dy < 3; ++dy) {
            const int yy = y + dy - 1;
            if (yy < 0 || yy > 63) {
                #pragma unroll
                for (int j = 0; j < 10; ++j) r[dy][j] = 0.f;
            } else {
                f16x8 v = *(const f16x8*)&smh[yy * 72 + c0];
                #pragma unroll
                for (int j = 0; j < 8; ++j) r[dy][j + 1] = (float)v[j];
                r[dy][0] = (c0 > 0)  ? (float)smh[yy * 72 + c0 - 1] : 0.f;
                r[dy][9] = (c0 < 56) ? (float)smh[yy * 72 + c0 + 8] : 0.f;
            }
        }
        f16x8 o;
        #pragma unroll
        for (int j = 0; j < 8; ++j) {
            float s = 0.f;
            #pragma unroll
            for (int dy = 0; dy < 3; ++dy)
                #pragma unroll
                for (int dx = 0; dx < 3; ++dx)
                    s = fmaf(w[dy * 3 + dx], r[dy][j + dx], s);
            o[j] = (_Float16)s;
            ssq = fmaf(s, s, ssq);
        }
        *(f16x8*)&g[u * 8] = o;             // reads come from LDS -> no hazard
    }
    if (ch < 2 * C_) {
        #pragma unroll
        for (int m = 1; m < 64; m <<= 1) ssq += __shfl_xor(ssq, m);
        if ((t & 63) == 0) wsum[t >> 6] = ssq;
        __syncthreads();
        if (t == 0) {
            float tot = wsum[0] + wsum[1] + wsum[2] + wsum[3];
            float inv = 1.f / fmaxf(sqrtf(tot), 1e-12f);
            (ch < C_ ? nqinv : nkinv)[b * C_ + (ch % C_)] = inv;
        }
    }
}

// ---------------- MFMA scores: sp[ks][bh][48][48], ksplit=4, 4 waves/block ----------------
__global__ __launch_bounds__(256) void scores_mfma(
    const _Float16* __restrict__ buf, float* __restrict__ sp)
{
    const int bh = blockIdx.x;              // 0..127
    const int ks = blockIdx.y;              // 0..3
    const int b = bh >> 3, h = bh & 7;
    const _Float16* qbase = buf + ((size_t)b * C3_ + (size_t)h * D_) * HW_;
    const _Float16* kbase = qbase + (size_t)C_ * HW_;
    const int t = threadIdx.x, l = t & 63, w = t >> 6;
    const int frow = l & 15, kseg = (l >> 4) * 8;
    const int p0 = ks * 1024 + w * 256;     // this wave's 256-pixel slice

    f32x4 acc[3][3] = {};
    #pragma unroll 2
    for (int st = 0; st < 8; ++st) {
        const int p = p0 + st * 32 + kseg;
        f16x8 qf[3], kf[3];
        #pragma unroll
        for (int mi = 0; mi < 3; ++mi)
            qf[mi] = *(const f16x8*)&qbase[(size_t)(mi * 16 + frow) * HW_ + p];
        #pragma unroll
        for (int ni = 0; ni < 3; ++ni)
            kf[ni] = *(const f16x8*)&kbase[(size_t)(ni * 16 + frow) * HW_ + p];
        #pragma unroll
        for (int mi = 0; mi < 3; ++mi)
            #pragma unroll
            for (int ni = 0; ni < 3; ++ni)
                acc[mi][ni] = __builtin_amdgcn_mfma_f32_16x16x32_f16(
                    qf[mi], kf[ni], acc[mi][ni], 0, 0, 0);   // D[d][e]
    }
    __shared__ float red[4][D_ * D_];
    #pragma unroll
    for (int mi = 0; mi < 3; ++mi)
        #pragma unroll
        for (int ni = 0; ni < 3; ++ni)
            #pragma unroll
            for (int r = 0; r < 4; ++r)
                red[w][(mi * 16 + (l >> 4) * 4 + r) * D_ + ni * 16 + (l & 15)] =
                    acc[mi][ni][r];
    __syncthreads();
    float* out = sp + ((size_t)ks * 128 + bh) * (D_ * D_);
    const float* rf = &red[0][0];
    for (int i = t; i < D_ * D_; i += 256)
        out[i] = rf[i] + rf[2304 + i] + rf[4608 + i] + rf[6912 + i];
}

// ---------------- reduce partials, scale, softmax (4 rows / block) ----------------
__global__ __launch_bounds__(256) void softmax_k(
    const float* __restrict__ sp, const float* __restrict__ nqinv,
    const float* __restrict__ nkinv, const float* __restrict__ temp,
    float* __restrict__ attn)
{
    const int row = blockIdx.x * 4 + (threadIdx.x >> 6);
    const int bh = row / D_, d = row % D_;
    const int h = bh & 7;
    const int e = threadIdx.x & 63;
    float s = -INFINITY;
    if (e < D_) {
        float raw = 0.f;
        #pragma unroll
        for (int ks = 0; ks < 4; ++ks)
            raw += sp[((size_t)ks * 128 + bh) * (D_ * D_) + d * D_ + e];
        s = raw * nqinv[bh * D_ + d] * nkinv[bh * D_ + e] * temp[h];
    }
    float m = s;
    #pragma unroll
    for (int off = 1; off < 64; off <<= 1) m = fmaxf(m, __shfl_xor(m, off));
    float p = (e < D_) ? expf(s - m) : 0.f;
    float sum = p;
    #pragma unroll
    for (int off = 1; off < 64; off <<= 1) sum += __shfl_xor(sum, off);
    if (e < D_) attn[(size_t)bh * (D_ * D_) + d * D_ + e] = p / sum;
}

// ---------------- attn @ v -> fp16 transposed [pixel][384] into q-plane region ----------------
__global__ __launch_bounds__(256) void pv_kernel(
    _Float16* __restrict__ buf, const float* __restrict__ attn)
{
    const int b = blockIdx.z, h = blockIdx.y;
    const int p0 = blockIdx.x * 512 + threadIdx.x * 2;
    __shared__ float a4[48][48];
    const float* ab = attn + ((size_t)b * 8 + h) * (D_ * D_);
    for (int i = threadIdx.x; i < D_ * D_; i += 256) ((float*)a4)[i] = ab[i];
    __syncthreads();
    const _Float16* vbase = buf + ((size_t)b * C3_ + 2 * C_ + (size_t)h * D_) * HW_;
    float2 acc[48];
    #pragma unroll
    for (int d = 0; d < 48; ++d) { acc[d].x = 0.f; acc[d].y = 0.f; }
    #pragma unroll 1
    for (int e4 = 0; e4 < 12; ++e4) {
        float2 vv[4];
        #pragma unroll
        for (int j = 0; j < 4; ++j) {
            f16x2 h2 = *(const f16x2*)&vbase[(size_t)(e4 * 4 + j) * HW_ + p0];
            vv[j].x = (float)h2[0]; vv[j].y = (float)h2[1];
        }
        #pragma unroll
        for (int d = 0; d < 48; ++d) {
            float4 a = *(const float4*)&a4[d][e4 * 4];
            acc[d].x = fmaf(a.x, vv[0].x, fmaf(a.y, vv[1].x, fmaf(a.z, vv[2].x, fmaf(a.w, vv[3].x, acc[d].x))));
            acc[d].y = fmaf(a.x, vv[0].y, fmaf(a.y, vv[1].y, fmaf(a.z, vv[2].y, fmaf(a.w, vv[3].y, acc[d].y))));
        }
    }
    _Float16* xt2b = buf + (size_t)b * C3_ * HW_;   // q region, dead now
    #pragma unroll
    for (int px = 0; px < 2; ++px) {
        f16x8 tmp[6];
        #pragma unroll
        for (int d = 0; d < 48; ++d) tmp[d >> 3][d & 7] = (_Float16)(px ? acc[d].y : acc[d].x);
        f16x8* dst = (f16x8*)&xt2b[(size_t)(p0 + px) * C_ + h * D_];
        #pragma unroll
        for (int j = 0; j < 6; ++j) dst[j] = tmp[j];
    }
}

extern "C" void kernel_launch(void* const* d_in, const int* in_sizes, int n_in,
                              void* d_out, int out_size, void* d_ws, size_t ws_size,
                              hipStream_t stream)
{
    const float* x      = (const float*)d_in[0];
    const float* w_qkv  = (const float*)d_in[1];
    const float* w_dw   = (const float*)d_in[2];
    const float* w_proj = (const float*)d_in[3];
    const float* temp   = (const float*)d_in[4];
    float* out = (float*)d_out;

    _Float16* buf = (_Float16*)d_ws;                       // 16*1152*4096 halves
    float* nqinv = (float*)(buf + (size_t)B_ * C3_ * HW_); // 6144 f
    float* nkinv = nqinv + 6144;
    float* sp    = nkinv + 6144;                           // 4*128*2304 f
    float* attn  = sp + (size_t)4 * 128 * D_ * D_;         // 128*2304 f
    _Float16* wqkv_h  = (_Float16*)(attn + (size_t)128 * D_ * D_);
    _Float16* wproj_h = wqkv_h + (size_t)C3_ * C_;
    _Float16* xt1     = wproj_h + (size_t)C_ * C_;         // 16*4096*384 halves

    // 0) weight + input conversion
    conv_w_f16<<<(C3_ * C_ / 4 + 255) / 256, 256, 0, stream>>>(w_qkv, wqkv_h, C3_ * C_ / 4);
    conv_w_f16<<<(C_ * C_ / 4 + 255) / 256, 256, 0, stream>>>(w_proj, wproj_h, C_ * C_ / 4);
    transpose_to_f16<<<dim3(64, 6, 16), 256, 0, stream>>>(x, xt1);

    // 1) qkv = w_qkv @ x (fp16 MFMA, 128x256 tile, depth-3 counted-vmcnt, fp16 out)
    mfma_gemm<C3_, false><<<dim3(9 * 16 * 16), 256, 0, stream>>>(
        wqkv_h, xt1, buf, (long long)HW_ * C_, (long long)C3_ * HW_);

    // 2) depthwise 3x3 SAME in place + fused q/k row norms
    dwconv_norm<<<B_ * C3_, 256, 0, stream>>>(buf, w_dw, nqinv, nkinv);

    // 3) raw score partials via MFMA (K split 4)
    scores_mfma<<<dim3(128, 4), 256, 0, stream>>>(buf, sp);

    // 4) reduce + scale + softmax
    softmax_k<<<1536, 256, 0, stream>>>(sp, nqinv, nkinv, temp, attn);

    // 5) attn @ v -> fp16 transposed into q region
    pv_kernel<<<dim3(8, 8, 16), 256, 0, stream>>>(buf, attn);

    // 6) out = w_proj @ attn_out (fp32 out)
    mfma_gemm<C_, true><<<dim3(3 * 16 * 16), 256, 0, stream>>>(
        wproj_h, buf, out, (long long)C3_ * HW_, (long long)C_ * HW_);
}